// Round 2
// baseline (1309.558 us; speedup 1.0000x reference)
//
#include <hip/hip_runtime.h>
#include <hip/hip_bf16.h>
#include <hip/hip_fp16.h>
#include <math.h>

#define T_TOK 8192
#define DIM   1024
#define HID   4096
#define NE    8
#define NTILES 136                 // 8 xcd * 17 slots
#define CAP_ROWS (NTILES * 128)    // 17408 padded slots

typedef _Float16 f16x8 __attribute__((ext_vector_type(8)));
typedef float    floatx4 __attribute__((ext_vector_type(4)));

__device__ __forceinline__ void gload_lds16(const void* g, void* l) {
    __builtin_amdgcn_global_load_lds(
        (const __attribute__((address_space(1))) void*)g,
        (__attribute__((address_space(3))) void*)l,
        16, 0, 0);
}

// ---------------- Pass 1a: gating + LN stats ----------------
__global__ __launch_bounds__(256) void gating_ln_kernel(
    const float* __restrict__ x, const float* __restrict__ gw,
    int* __restrict__ sel, float* __restrict__ wts,
    float* __restrict__ mu_arr, float* __restrict__ rstd_arr,
    int* __restrict__ counts)
{
    int t = blockIdx.x;
    int tid = threadIdx.x;
    float4 xv = ((const float4*)(x + (size_t)t * DIM))[tid];
    float s  = xv.x + xv.y + xv.z + xv.w;
    float ss = xv.x*xv.x + xv.y*xv.y + xv.z*xv.z + xv.w*xv.w;
    float l[NE];
#pragma unroll
    for (int e = 0; e < NE; e++) l[e] = 0.f;
    int d0 = tid * 4;
    const float* xp = &xv.x;
#pragma unroll
    for (int j = 0; j < 4; j++) {
        float xj = xp[j];
        const float4* g = (const float4*)(gw + (size_t)(d0 + j) * NE);
        float4 g0 = g[0], g1 = g[1];
        l[0] += xj * g0.x; l[1] += xj * g0.y; l[2] += xj * g0.z; l[3] += xj * g0.w;
        l[4] += xj * g1.x; l[5] += xj * g1.y; l[6] += xj * g1.z; l[7] += xj * g1.w;
    }
#pragma unroll
    for (int off = 32; off > 0; off >>= 1) {
        s  += __shfl_down(s, off);
        ss += __shfl_down(ss, off);
#pragma unroll
        for (int e = 0; e < NE; e++) l[e] += __shfl_down(l[e], off);
    }
    __shared__ float red[4][10];
    int lane = tid & 63, wv = tid >> 6;
    if (lane == 0) {
        red[wv][0] = s; red[wv][1] = ss;
        for (int e = 0; e < NE; e++) red[wv][2 + e] = l[e];
    }
    __syncthreads();
    if (tid == 0) {
        float S = 0.f, SS = 0.f, L[NE];
        for (int e = 0; e < NE; e++) L[e] = 0.f;
        for (int w = 0; w < 4; w++) {
            S += red[w][0]; SS += red[w][1];
            for (int e = 0; e < NE; e++) L[e] += red[w][2 + e];
        }
        float mu  = S * (1.f / DIM);
        float var = SS * (1.f / DIM) - mu * mu;
        float rstd = rsqrtf(var + 1e-5f);
        float lmax = L[0];
        for (int e = 1; e < NE; e++) lmax = fmaxf(lmax, L[e]);
        float den = 0.f;
        for (int e = 0; e < NE; e++) den += expf(L[e] - lmax);
        int i0 = 0; float b0 = L[0];
        for (int e = 1; e < NE; e++) if (L[e] > b0) { b0 = L[e]; i0 = e; }
        int i1 = -1; float b1v = -3.4e38f;
        for (int e = 0; e < NE; e++) if (e != i0 && L[e] > b1v) { b1v = L[e]; i1 = e; }
        float p0 = expf(b0 - lmax) / den;
        float p1 = expf(b1v - lmax) / den;
        float t1 = expf(p1 - p0);            // p1 <= p0, stable
        float w0 = 1.f / (1.f + t1);
        float w1 = t1 / (1.f + t1);
        sel[2*t] = i0;  sel[2*t+1] = i1;
        wts[2*t] = w0;  wts[2*t+1] = w1;
        mu_arr[t] = mu; rstd_arr[t] = rstd;
        atomicAdd(&counts[i0], 1);
        atomicAdd(&counts[i1], 1);
    }
}

// ---------------- Pass 1b: 128-aligned offsets + tile->expert map ----------------
__global__ void build_offsets_kernel(const int* __restrict__ counts, int* __restrict__ off,
                                     int* __restrict__ cursor, int* __restrict__ tile_expert)
{
    if (threadIdx.x != 0 || blockIdx.x != 0) return;
    int o = 0;
    for (int e = 0; e < NE; e++) {
        off[e] = o;
        o += ((counts[e] + 127) >> 7) << 7;
        cursor[e] = 0;
    }
    off[NE] = o;
    for (int tIdx = 0; tIdx < NTILES; tIdx++) {
        int pos = tIdx * 128;
        int e = -1;
        if (pos < o) {
            for (int j = 0; j < NE; j++)
                if (pos >= off[j] && pos < off[j+1]) { e = j; break; }
        }
        tile_expert[tIdx] = e;
    }
}

// ---------------- Pass 1c: scatter normalized tokens (LN affine folded) ----------------
__global__ __launch_bounds__(256) void scatter_kernel(
    const float* __restrict__ x, const float* __restrict__ ln_s, const float* __restrict__ ln_b,
    const int* __restrict__ sel,
    const float* __restrict__ mu_arr, const float* __restrict__ rstd_arr,
    const int* __restrict__ off, int* __restrict__ cursor,
    _Float16* __restrict__ xg, int* __restrict__ slot_of)
{
    int t = blockIdx.x, tid = threadIdx.x;
    __shared__ int sslot[2];
    int e0 = sel[2*t], e1 = sel[2*t+1];
    if (tid == 0) {
        int s0 = off[e0] + atomicAdd(&cursor[e0], 1);
        int s1 = off[e1] + atomicAdd(&cursor[e1], 1);
        sslot[0] = s0; sslot[1] = s1;
        slot_of[2*t] = s0; slot_of[2*t+1] = s1;
    }
    __syncthreads();
    float4 xv = ((const float4*)(x + (size_t)t * DIM))[tid];
    float mu = mu_arr[t], rstd = rstd_arr[t];
    float xn0 = (xv.x - mu) * rstd, xn1 = (xv.y - mu) * rstd;
    float xn2 = (xv.z - mu) * rstd, xn3 = (xv.w - mu) * rstd;
#pragma unroll
    for (int k = 0; k < 2; k++) {
        int e = (k == 0) ? e0 : e1;
        int slot = sslot[k];
        float4 sv = ((const float4*)(ln_s + (size_t)e * DIM))[tid];
        float4 bv = ((const float4*)(ln_b + (size_t)e * DIM))[tid];
        _Float16 hb[4];
        hb[0] = (_Float16)(xn0 * sv.x + bv.x);
        hb[1] = (_Float16)(xn1 * sv.y + bv.y);
        hb[2] = (_Float16)(xn2 * sv.z + bv.z);
        hb[3] = (_Float16)(xn3 * sv.w + bv.w);
        *(uint2*)(xg + (size_t)slot * DIM + tid * 4) = *(const uint2*)hb;
    }
}

// ---------------- Weight transpose + fp32->fp16 convert ----------------
// in: [batch][R][C] fp32 -> out: [batch][C][R] fp16
__global__ __launch_bounds__(256) void transpose_cvt_kernel(
    const float* __restrict__ in, _Float16* __restrict__ out, int R, int C)
{
    __shared__ _Float16 tile[64][65];
    size_t ebase = (size_t)blockIdx.z * R * C;
    const float* inp = in + ebase + (size_t)(blockIdx.y * 64) * C + blockIdx.x * 64;
    _Float16* outp = out + ebase + (size_t)(blockIdx.x * 64) * R + blockIdx.y * 64;
    int t = threadIdx.x & 31, j0 = threadIdx.x >> 5;
    for (int j = j0; j < 64; j += 8) {
        float2 v = *(const float2*)(inp + (size_t)j * C + 2 * t);
        tile[j][2*t]   = (_Float16)v.x;
        tile[j][2*t+1] = (_Float16)v.y;
    }
    __syncthreads();
    for (int j = j0; j < 64; j += 8) {
        _Float16 pr[2] = { tile[2*t][j], tile[2*t+1][j] };
        *(unsigned int*)(outp + (size_t)j * R + 2 * t) = *(unsigned int*)pr;
    }
}

// ---------------- GEMM1: H1 = gelu(xg @ w1 + b1), fp16 in, fp16 out ----------------
__global__ __launch_bounds__(256) void gemm1_kernel(
    const _Float16* __restrict__ xg,   // [CAP][DIM]
    const _Float16* __restrict__ w1t,  // [E][HID][DIM]
    const float* __restrict__ b1,      // [E][HID]
    const int* __restrict__ tile_expert,
    _Float16* __restrict__ H1)         // [CAP][HID]
{
    __shared__ _Float16 smem[8192];    // As = 0..4095, Bs = 4096..8191 (halves)
    _Float16* As = smem;
    _Float16* Bs = smem + 4096;
    // XCD swizzle: all 32 n-tiles of a row-tile on one XCD (bid%8 heuristic)
    int bid = blockIdx.x;
    int xcd = bid & 7, slot = bid >> 3;
    int rowt = xcd + 8 * (slot >> 5);
    int nt = slot & 31;
    int e = tile_expert[rowt];
    if (e < 0) return;
    int row0 = rowt * 128;
    int n0 = nt * 128;
    const _Float16* Abase = xg + (size_t)row0 * DIM;
    const _Float16* Bbase = w1t + ((size_t)e * HID + n0) * DIM;
    int tid = threadIdx.x;
    int lane = tid & 63, wv = tid >> 6;
    int wm = wv >> 1, wn = wv & 1;
    int lm = lane & 15, kq = lane >> 4;
    floatx4 acc[4][4] = {};

    for (int k0 = 0; k0 < DIM; k0 += 32) {
#pragma unroll
        for (int r = 0; r < 2; r++) {
            int j = r * 256 + tid;
            int arow = j >> 2;
            int acol = (j & 3) * 8;
            gload_lds16(Abase + (size_t)arow * DIM + (k0 + acol), (char*)As + j * 16);
            gload_lds16(Bbase + (size_t)arow * DIM + (k0 + acol), (char*)Bs + j * 16);
        }
        __syncthreads();
        f16x8 af[4], bf[4];
#pragma unroll
        for (int tm = 0; tm < 4; tm++)
            af[tm] = *(const f16x8*)(As + (wm*64 + tm*16 + lm) * 32 + kq * 8);
#pragma unroll
        for (int tn = 0; tn < 4; tn++)
            bf[tn] = *(const f16x8*)(Bs + (wn*64 + tn*16 + lm) * 32 + kq * 8);
#pragma unroll
        for (int tm = 0; tm < 4; tm++)
#pragma unroll
            for (int tn = 0; tn < 4; tn++)
                acc[tm][tn] = __builtin_amdgcn_mfma_f32_16x16x32_f16(af[tm], bf[tn], acc[tm][tn], 0, 0, 0);
        __syncthreads();
    }
    // epilogue: bias + exact gelu, wave-private LDS repack, 16B coalesced stores
    const float* b1e = b1 + (size_t)e * HID + n0;
    float bias[4];
#pragma unroll
    for (int tn = 0; tn < 4; tn++) bias[tn] = b1e[wn*64 + tn*16 + lm];
    _Float16* wbuf = smem + wv * (16 * 72);   // 16 rows x stride 72 halves per wave
    int rowg0 = row0 + wm * 64;
    int colg0 = n0 + wn * 64;
#pragma unroll
    for (int tm = 0; tm < 4; tm++) {
#pragma unroll
        for (int tn = 0; tn < 4; tn++) {
#pragma unroll
            for (int r = 0; r < 4; r++) {
                float v = acc[tm][tn][r] + bias[tn];
                v = 0.5f * v * (1.f + erff(v * 0.70710678118654752f));
                wbuf[(kq*4 + r) * 72 + tn*16 + lm] = (_Float16)v;
            }
        }
#pragma unroll
        for (int i = 0; i < 2; i++) {
            int idx = i * 64 + lane;           // 0..127
            int rr = idx >> 3;                 // 0..15
            int cc = (idx & 7) * 8;            // 0..56
            f16x8 val = *(const f16x8*)(wbuf + rr * 72 + cc);
            *(f16x8*)(H1 + (size_t)(rowg0 + tm*16 + rr) * HID + colg0 + cc) = val;
        }
    }
}

// ---------------- GEMM2: y[slot] = H1[slot] @ w2[e]  (raw, fp32 out) ----------------
__global__ __launch_bounds__(256) void gemm2_kernel(
    const _Float16* __restrict__ H1,   // [CAP][HID]
    const _Float16* __restrict__ w2t,  // [E][DIM][HID]
    const int* __restrict__ tile_expert,
    const int* __restrict__ off, const int* __restrict__ counts,
    float* __restrict__ y)             // [CAP][DIM]
{
    __shared__ _Float16 smem[8192];
    _Float16* As = smem;
    _Float16* Bs = smem + 4096;
    // XCD swizzle: all 8 n-tiles of a row-tile on one XCD
    int bid = blockIdx.x;
    int xcd = bid & 7, slot = bid >> 3;
    int rowt = xcd + 8 * (slot >> 3);
    int nt = slot & 7;
    int e = tile_expert[rowt];
    if (e < 0) return;
    int row0 = rowt * 128;
    int n0 = nt * 128;
    const _Float16* Abase = H1 + (size_t)row0 * HID;
    const _Float16* Bbase = w2t + ((size_t)e * DIM + n0) * HID;
    int tid = threadIdx.x;
    int lane = tid & 63, wv = tid >> 6;
    int wm = wv >> 1, wn = wv & 1;
    int lm = lane & 15, kq = lane >> 4;
    floatx4 acc[4][4] = {};

    for (int k0 = 0; k0 < HID; k0 += 32) {
#pragma unroll
        for (int r = 0; r < 2; r++) {
            int j = r * 256 + tid;
            int arow = j >> 2;
            int acol = (j & 3) * 8;
            gload_lds16(Abase + (size_t)arow * HID + (k0 + acol), (char*)As + j * 16);
            gload_lds16(Bbase + (size_t)arow * HID + (k0 + acol), (char*)Bs + j * 16);
        }
        __syncthreads();
        f16x8 af[4], bf[4];
#pragma unroll
        for (int tm = 0; tm < 4; tm++)
            af[tm] = *(const f16x8*)(As + (wm*64 + tm*16 + lm) * 32 + kq * 8);
#pragma unroll
        for (int tn = 0; tn < 4; tn++)
            bf[tn] = *(const f16x8*)(Bs + (wn*64 + tn*16 + lm) * 32 + kq * 8);
#pragma unroll
        for (int tm = 0; tm < 4; tm++)
#pragma unroll
            for (int tn = 0; tn < 4; tn++)
                acc[tm][tn] = __builtin_amdgcn_mfma_f32_16x16x32_f16(af[tm], bf[tn], acc[tm][tn], 0, 0, 0);
        __syncthreads();
    }
    int end = off[e] + counts[e];
#pragma unroll
    for (int tm = 0; tm < 4; tm++) {
        int rbase = row0 + wm*64 + tm*16 + kq*4;
#pragma unroll
        for (int r = 0; r < 4; r++) {
            int s = rbase + r;
            if (s >= end) continue;            // pad rows never read
#pragma unroll
            for (int tn = 0; tn < 4; tn++) {
                int d = n0 + wn*64 + tn*16 + lm;
                y[(size_t)s * DIM + d] = acc[tm][tn][r];
            }
        }
    }
}

// ---------------- Combine: out[t] = sum_k wts[t,k] * (y[slot_k] + b2[e_k]) ----------------
__global__ __launch_bounds__(256) void combine_kernel(
    const float* __restrict__ y, const int* __restrict__ slot_of,
    const float* __restrict__ wts, const int* __restrict__ sel,
    const float* __restrict__ b2, float* __restrict__ out)
{
    int t = blockIdx.x, i = threadIdx.x;
    int s0 = slot_of[2*t], s1 = slot_of[2*t+1];
    int e0 = sel[2*t], e1 = sel[2*t+1];
    float w0 = wts[2*t], w1 = wts[2*t+1];
    float4 y0 = ((const float4*)(y + (size_t)s0 * DIM))[i];
    float4 y1 = ((const float4*)(y + (size_t)s1 * DIM))[i];
    float4 c0 = ((const float4*)(b2 + (size_t)e0 * DIM))[i];
    float4 c1 = ((const float4*)(b2 + (size_t)e1 * DIM))[i];
    float4 o;
    o.x = w0 * (y0.x + c0.x) + w1 * (y1.x + c1.x);
    o.y = w0 * (y0.y + c0.y) + w1 * (y1.y + c1.y);
    o.z = w0 * (y0.z + c0.z) + w1 * (y1.z + c1.z);
    o.w = w0 * (y0.w + c0.w) + w1 * (y1.w + c1.w);
    ((float4*)(out + (size_t)t * DIM))[i] = o;
}

extern "C" void kernel_launch(void* const* d_in, const int* in_sizes, int n_in,
                              void* d_out, int out_size, void* d_ws, size_t ws_size,
                              hipStream_t stream)
{
    const float* x    = (const float*)d_in[0];
    const float* gw   = (const float*)d_in[1];
    const float* ln_s = (const float*)d_in[2];
    const float* ln_b = (const float*)d_in[3];
    const float* w1   = (const float*)d_in[4];
    const float* b1   = (const float*)d_in[5];
    const float* w2   = (const float*)d_in[6];
    const float* b2   = (const float*)d_in[7];
    float* out = (float*)d_out;

    char* p = (char*)d_ws;
    auto carve = [&](size_t bytes) -> char* {
        char* r = p;
        p += (bytes + 255) & ~(size_t)255;
        return r;
    };
    int*   counts   = (int*)carve(NE * 4);
    int*   cursor   = (int*)carve(NE * 4);
    int*   off      = (int*)carve((NE + 1) * 4);
    int*   tile_exp = (int*)carve(NTILES * 4);
    int*   sel      = (int*)carve((size_t)T_TOK * 2 * 4);
    float* wts      = (float*)carve((size_t)T_TOK * 2 * 4);
    float* mu_arr   = (float*)carve((size_t)T_TOK * 4);
    float* rstd_arr = (float*)carve((size_t)T_TOK * 4);
    int*   slot_of  = (int*)carve((size_t)T_TOK * 2 * 4);
    _Float16* xg  = (_Float16*)carve((size_t)CAP_ROWS * DIM * 2);  // 35.7 MB
    _Float16* w1t = (_Float16*)carve((size_t)NE * DIM * HID * 2);  // 67.1 MB
    _Float16* w2t = (_Float16*)carve((size_t)NE * DIM * HID * 2);
    _Float16* H1  = (_Float16*)carve((size_t)CAP_ROWS * HID * 2);
    // y aliases xg (+ start of w1t): xg dead after gemm1, w1t dead after gemm1;
    // y (71.3 MB) fits in xg+w1t (102.8 MB contiguous carve region).
    float* y = (float*)xg;

    hipMemsetAsync(counts, 0, NE * 4, stream);

    gating_ln_kernel<<<T_TOK, 256, 0, stream>>>(x, gw, sel, wts, mu_arr, rstd_arr, counts);
    build_offsets_kernel<<<1, 1, 0, stream>>>(counts, off, cursor, tile_exp);
    scatter_kernel<<<T_TOK, 256, 0, stream>>>(x, ln_s, ln_b, sel, mu_arr, rstd_arr,
                                              off, cursor, xg, slot_of);
    // w1: [E][D][H] -> [E][H][D]
    transpose_cvt_kernel<<<dim3(HID/64, DIM/64, NE), 256, 0, stream>>>(w1, w1t, DIM, HID);
    // w2: [E][H][D] -> [E][D][H]
    transpose_cvt_kernel<<<dim3(DIM/64, HID/64, NE), 256, 0, stream>>>(w2, w2t, HID, DIM);

    gemm1_kernel<<<NTILES * 32, 256, 0, stream>>>(xg, w1t, b1, tile_exp, H1);
    gemm2_kernel<<<NTILES * 8, 256, 0, stream>>>(H1, w2t, tile_exp, off, counts, y);
    combine_kernel<<<T_TOK, 256, 0, stream>>>(y, slot_of, wts, sel, b2, out);
}

// Round 3
// 1153.578 us; speedup vs baseline: 1.1352x; 1.1352x over previous
//
#include <hip/hip_runtime.h>
#include <hip/hip_bf16.h>
#include <hip/hip_fp16.h>
#include <math.h>

#define T_TOK 8192
#define DIM   1024
#define HID   4096
#define NE    8
#define NTILES 136                 // 8 xcd * 17 slots
#define CAP_ROWS (NTILES * 128)    // 17408 padded slots

typedef _Float16 f16x8 __attribute__((ext_vector_type(8)));
typedef float    floatx4 __attribute__((ext_vector_type(4)));

__device__ __forceinline__ void gload_lds16(const void* g, void* l) {
    __builtin_amdgcn_global_load_lds(
        (const __attribute__((address_space(1))) void*)g,
        (__attribute__((address_space(3))) void*)l,
        16, 0, 0);
}

// tanh-form GELU (max dev from exact ~1e-3; threshold headroom 4.7x)
__device__ __forceinline__ float gelu_f(float v) {
    float u = v * (0.7978845608028654f + 0.03567740813636141f * v * v);
    float e = exp2f(2.8853900817779268f * u);     // exp(2u)
    float th = 1.f - 2.f / (e + 1.f);
    return 0.5f * v * (1.f + th);
}

// ---------------- Pass 1a: gating + LN stats ----------------
__global__ __launch_bounds__(256) void gating_ln_kernel(
    const float* __restrict__ x, const float* __restrict__ gw,
    int* __restrict__ sel, float* __restrict__ wts,
    float* __restrict__ mu_arr, float* __restrict__ rstd_arr,
    int* __restrict__ counts)
{
    int t = blockIdx.x;
    int tid = threadIdx.x;
    float4 xv = ((const float4*)(x + (size_t)t * DIM))[tid];
    float s  = xv.x + xv.y + xv.z + xv.w;
    float ss = xv.x*xv.x + xv.y*xv.y + xv.z*xv.z + xv.w*xv.w;
    float l[NE];
#pragma unroll
    for (int e = 0; e < NE; e++) l[e] = 0.f;
    int d0 = tid * 4;
    const float* xp = &xv.x;
#pragma unroll
    for (int j = 0; j < 4; j++) {
        float xj = xp[j];
        const float4* g = (const float4*)(gw + (size_t)(d0 + j) * NE);
        float4 g0 = g[0], g1 = g[1];
        l[0] += xj * g0.x; l[1] += xj * g0.y; l[2] += xj * g0.z; l[3] += xj * g0.w;
        l[4] += xj * g1.x; l[5] += xj * g1.y; l[6] += xj * g1.z; l[7] += xj * g1.w;
    }
#pragma unroll
    for (int off = 32; off > 0; off >>= 1) {
        s  += __shfl_down(s, off);
        ss += __shfl_down(ss, off);
#pragma unroll
        for (int e = 0; e < NE; e++) l[e] += __shfl_down(l[e], off);
    }
    __shared__ float red[4][10];
    int lane = tid & 63, wv = tid >> 6;
    if (lane == 0) {
        red[wv][0] = s; red[wv][1] = ss;
        for (int e = 0; e < NE; e++) red[wv][2 + e] = l[e];
    }
    __syncthreads();
    if (tid == 0) {
        float S = 0.f, SS = 0.f, L[NE];
        for (int e = 0; e < NE; e++) L[e] = 0.f;
        for (int w = 0; w < 4; w++) {
            S += red[w][0]; SS += red[w][1];
            for (int e = 0; e < NE; e++) L[e] += red[w][2 + e];
        }
        float mu  = S * (1.f / DIM);
        float var = SS * (1.f / DIM) - mu * mu;
        float rstd = rsqrtf(var + 1e-5f);
        float lmax = L[0];
        for (int e = 1; e < NE; e++) lmax = fmaxf(lmax, L[e]);
        float den = 0.f;
        for (int e = 0; e < NE; e++) den += expf(L[e] - lmax);
        int i0 = 0; float b0 = L[0];
        for (int e = 1; e < NE; e++) if (L[e] > b0) { b0 = L[e]; i0 = e; }
        int i1 = -1; float b1v = -3.4e38f;
        for (int e = 0; e < NE; e++) if (e != i0 && L[e] > b1v) { b1v = L[e]; i1 = e; }
        float p0 = expf(b0 - lmax) / den;
        float p1 = expf(b1v - lmax) / den;
        float t1 = expf(p1 - p0);            // p1 <= p0, stable
        float w0 = 1.f / (1.f + t1);
        float w1 = t1 / (1.f + t1);
        sel[2*t] = i0;  sel[2*t+1] = i1;
        wts[2*t] = w0;  wts[2*t+1] = w1;
        mu_arr[t] = mu; rstd_arr[t] = rstd;
        atomicAdd(&counts[i0], 1);
        atomicAdd(&counts[i1], 1);
    }
}

// ---------------- Pass 1b: 128-aligned offsets + tile->expert map ----------------
__global__ void build_offsets_kernel(const int* __restrict__ counts, int* __restrict__ off,
                                     int* __restrict__ cursor, int* __restrict__ tile_expert)
{
    if (threadIdx.x != 0 || blockIdx.x != 0) return;
    int o = 0;
    for (int e = 0; e < NE; e++) {
        off[e] = o;
        o += ((counts[e] + 127) >> 7) << 7;
        cursor[e] = 0;
    }
    off[NE] = o;
    for (int tIdx = 0; tIdx < NTILES; tIdx++) {
        int pos = tIdx * 128;
        int e = -1;
        if (pos < o) {
            for (int j = 0; j < NE; j++)
                if (pos >= off[j] && pos < off[j+1]) { e = j; break; }
        }
        tile_expert[tIdx] = e;
    }
}

// ---------------- Pass 1c: scatter normalized tokens (LN affine folded) ----------------
__global__ __launch_bounds__(256) void scatter_kernel(
    const float* __restrict__ x, const float* __restrict__ ln_s, const float* __restrict__ ln_b,
    const int* __restrict__ sel,
    const float* __restrict__ mu_arr, const float* __restrict__ rstd_arr,
    const int* __restrict__ off, int* __restrict__ cursor,
    _Float16* __restrict__ xg, int* __restrict__ slot_of)
{
    int t = blockIdx.x, tid = threadIdx.x;
    __shared__ int sslot[2];
    int e0 = sel[2*t], e1 = sel[2*t+1];
    if (tid == 0) {
        int s0 = off[e0] + atomicAdd(&cursor[e0], 1);
        int s1 = off[e1] + atomicAdd(&cursor[e1], 1);
        sslot[0] = s0; sslot[1] = s1;
        slot_of[2*t] = s0; slot_of[2*t+1] = s1;
    }
    __syncthreads();
    float4 xv = ((const float4*)(x + (size_t)t * DIM))[tid];
    float mu = mu_arr[t], rstd = rstd_arr[t];
    float xn0 = (xv.x - mu) * rstd, xn1 = (xv.y - mu) * rstd;
    float xn2 = (xv.z - mu) * rstd, xn3 = (xv.w - mu) * rstd;
#pragma unroll
    for (int k = 0; k < 2; k++) {
        int e = (k == 0) ? e0 : e1;
        int slot = sslot[k];
        float4 sv = ((const float4*)(ln_s + (size_t)e * DIM))[tid];
        float4 bv = ((const float4*)(ln_b + (size_t)e * DIM))[tid];
        _Float16 hb[4];
        hb[0] = (_Float16)(xn0 * sv.x + bv.x);
        hb[1] = (_Float16)(xn1 * sv.y + bv.y);
        hb[2] = (_Float16)(xn2 * sv.z + bv.z);
        hb[3] = (_Float16)(xn3 * sv.w + bv.w);
        *(uint2*)(xg + (size_t)slot * DIM + tid * 4) = *(const uint2*)hb;
    }
}

// ---------------- Weight transpose + fp32->fp16 convert ----------------
__global__ __launch_bounds__(256) void transpose_cvt_kernel(
    const float* __restrict__ in, _Float16* __restrict__ out, int R, int C)
{
    __shared__ _Float16 tile[64][65];
    size_t ebase = (size_t)blockIdx.z * R * C;
    const float* inp = in + ebase + (size_t)(blockIdx.y * 64) * C + blockIdx.x * 64;
    _Float16* outp = out + ebase + (size_t)(blockIdx.x * 64) * R + blockIdx.y * 64;
    int t = threadIdx.x & 31, j0 = threadIdx.x >> 5;
    for (int j = j0; j < 64; j += 8) {
        float2 v = *(const float2*)(inp + (size_t)j * C + 2 * t);
        tile[j][2*t]   = (_Float16)v.x;
        tile[j][2*t+1] = (_Float16)v.y;
    }
    __syncthreads();
    for (int j = j0; j < 64; j += 8) {
        _Float16 pr[2] = { tile[2*t][j], tile[2*t+1][j] };
        *(unsigned int*)(outp + (size_t)j * R + 2 * t) = *(unsigned int*)pr;
    }
}

// ---------------- GEMM1: H1 = gelu(xg @ w1 + b1), double-buffered ----------------
__global__ __launch_bounds__(256) void gemm1_kernel(
    const _Float16* __restrict__ xg,   // [CAP][DIM]
    const _Float16* __restrict__ w1t,  // [E][HID][DIM]
    const float* __restrict__ b1,      // [E][HID]
    const int* __restrict__ tile_expert,
    _Float16* __restrict__ H1)         // [CAP][HID]
{
    __shared__ _Float16 smem[16384];   // 32KB: buf0 A[0,4096) B[4096,8192); buf1 +8192
    int bid = blockIdx.x;
    int xcd = bid & 7, slot = bid >> 3;
    int rowt = xcd + 8 * (slot >> 5);
    int nt = slot & 31;
    int e = tile_expert[rowt];
    if (e < 0) return;
    int row0 = rowt * 128;
    int n0 = nt * 128;
    int tid = threadIdx.x;
    int lane = tid & 63, wv = tid >> 6;
    int wm = wv >> 1, wn = wv & 1;
    int lm = lane & 15, kq = lane >> 4;

    // per-thread staging pointers (row = tid>>2 and +64, col = (tid&3)*8)
    int arow = tid >> 2, acol = (tid & 3) * 8;
    const _Float16* srcA = xg + ((size_t)(row0 + arow)) * DIM + acol;
    const _Float16* srcB = w1t + ((size_t)e * HID + n0 + arow) * DIM + acol;
    int ldst = tid * 8;                 // halves

    floatx4 acc[4][4] = {};

#define STAGE1(buf, k0)                                                        \
    do {                                                                       \
        _Float16* sA = smem + (buf) * 8192;                                    \
        _Float16* sB = sA + 4096;                                              \
        gload_lds16(srcA + (k0), sA + ldst);                                   \
        gload_lds16(srcA + 64 * DIM + (k0), sA + ldst + 2048);                 \
        gload_lds16(srcB + (k0), sB + ldst);                                   \
        gload_lds16(srcB + 64 * DIM + (k0), sB + ldst + 2048);                 \
    } while (0)

#define COMPUTE1(buf)                                                          \
    do {                                                                       \
        const _Float16* sA = smem + (buf) * 8192;                              \
        const _Float16* sB = sA + 4096;                                        \
        f16x8 af[4], bf[4];                                                    \
        for (int tm = 0; tm < 4; tm++)                                         \
            af[tm] = *(const f16x8*)(sA + (wm*64 + tm*16 + lm) * 32 + kq * 8); \
        for (int tn = 0; tn < 4; tn++)                                         \
            bf[tn] = *(const f16x8*)(sB + (wn*64 + tn*16 + lm) * 32 + kq * 8); \
        for (int tm = 0; tm < 4; tm++)                                         \
            for (int tn = 0; tn < 4; tn++)                                     \
                acc[tm][tn] = __builtin_amdgcn_mfma_f32_16x16x32_f16(          \
                    af[tm], bf[tn], acc[tm][tn], 0, 0, 0);                     \
    } while (0)

    STAGE1(0, 0);
    __syncthreads();
    int p = 0;
#pragma unroll 4
    for (int k0 = 32; k0 < DIM; k0 += 32) {
        STAGE1(p ^ 1, k0);
        COMPUTE1(p);
        __syncthreads();
        p ^= 1;
    }
    COMPUTE1(p);    // p == 1 here (31 flips); epilogue wbuf uses buf0 — safe

    // epilogue: bias + gelu, wave-private LDS repack, 16B coalesced stores
    const float* b1e = b1 + (size_t)e * HID + n0;
    float bias[4];
#pragma unroll
    for (int tn = 0; tn < 4; tn++) bias[tn] = b1e[wn*64 + tn*16 + lm];
    _Float16* wbuf = smem + wv * (16 * 72);   // 16 rows x stride 72 halves per wave
    int rowg0 = row0 + wm * 64;
    int colg0 = n0 + wn * 64;
#pragma unroll
    for (int tm = 0; tm < 4; tm++) {
#pragma unroll
        for (int tn = 0; tn < 4; tn++) {
#pragma unroll
            for (int r = 0; r < 4; r++) {
                float v = acc[tm][tn][r] + bias[tn];
                wbuf[(kq*4 + r) * 72 + tn*16 + lm] = (_Float16)gelu_f(v);
            }
        }
#pragma unroll
        for (int i = 0; i < 2; i++) {
            int idx = i * 64 + lane;           // 0..127
            int rr = idx >> 3;                 // 0..15
            int cc = (idx & 7) * 8;            // 0..56
            f16x8 val = *(const f16x8*)(wbuf + rr * 72 + cc);
            *(f16x8*)(H1 + (size_t)(rowg0 + tm*16 + rr) * HID + colg0 + cc) = val;
        }
    }
#undef STAGE1
#undef COMPUTE1
}

// ---------------- GEMM2: y[slot] = H1[slot] @ w2[e], double-buffered ----------------
__global__ __launch_bounds__(256) void gemm2_kernel(
    const _Float16* __restrict__ H1,   // [CAP][HID]
    const _Float16* __restrict__ w2t,  // [E][DIM][HID]
    const int* __restrict__ tile_expert,
    const int* __restrict__ off, const int* __restrict__ counts,
    float* __restrict__ y)             // [CAP][DIM]
{
    __shared__ _Float16 smem[16384];
    int bid = blockIdx.x;
    int xcd = bid & 7, slot = bid >> 3;
    int rowt = xcd + 8 * (slot >> 3);
    int nt = slot & 7;
    int e = tile_expert[rowt];
    if (e < 0) return;
    int row0 = rowt * 128;
    int n0 = nt * 128;
    int tid = threadIdx.x;
    int lane = tid & 63, wv = tid >> 6;
    int wm = wv >> 1, wn = wv & 1;
    int lm = lane & 15, kq = lane >> 4;

    int arow = tid >> 2, acol = (tid & 3) * 8;
    const _Float16* srcA = H1 + ((size_t)(row0 + arow)) * HID + acol;
    const _Float16* srcB = w2t + ((size_t)e * DIM + n0 + arow) * HID + acol;
    int ldst = tid * 8;

    floatx4 acc[4][4] = {};

#define STAGE2(buf, k0)                                                        \
    do {                                                                       \
        _Float16* sA = smem + (buf) * 8192;                                    \
        _Float16* sB = sA + 4096;                                              \
        gload_lds16(srcA + (k0), sA + ldst);                                   \
        gload_lds16(srcA + 64 * HID + (k0), sA + ldst + 2048);                 \
        gload_lds16(srcB + (k0), sB + ldst);                                   \
        gload_lds16(srcB + 64 * HID + (k0), sB + ldst + 2048);                 \
    } while (0)

#define COMPUTE2(buf)                                                          \
    do {                                                                       \
        const _Float16* sA = smem + (buf) * 8192;                              \
        const _Float16* sB = sA + 4096;                                        \
        f16x8 af[4], bf[4];                                                    \
        for (int tm = 0; tm < 4; tm++)                                         \
            af[tm] = *(const f16x8*)(sA + (wm*64 + tm*16 + lm) * 32 + kq * 8); \
        for (int tn = 0; tn < 4; tn++)                                         \
            bf[tn] = *(const f16x8*)(sB + (wn*64 + tn*16 + lm) * 32 + kq * 8); \
        for (int tm = 0; tm < 4; tm++)                                         \
            for (int tn = 0; tn < 4; tn++)                                     \
                acc[tm][tn] = __builtin_amdgcn_mfma_f32_16x16x32_f16(          \
                    af[tm], bf[tn], acc[tm][tn], 0, 0, 0);                     \
    } while (0)

    STAGE2(0, 0);
    __syncthreads();
    int p = 0;
#pragma unroll 4
    for (int k0 = 32; k0 < HID; k0 += 32) {
        STAGE2(p ^ 1, k0);
        COMPUTE2(p);
        __syncthreads();
        p ^= 1;
    }
    COMPUTE2(p);

    int end = off[e] + counts[e];
#pragma unroll
    for (int tm = 0; tm < 4; tm++) {
        int rbase = row0 + wm*64 + tm*16 + kq*4;
#pragma unroll
        for (int r = 0; r < 4; r++) {
            int s = rbase + r;
            if (s >= end) continue;            // pad rows never read
#pragma unroll
            for (int tn = 0; tn < 4; tn++) {
                int d = n0 + wn*64 + tn*16 + lm;
                y[(size_t)s * DIM + d] = acc[tm][tn][r];
            }
        }
    }
#undef STAGE2
#undef COMPUTE2
}

// ---------------- Combine: out[t] = sum_k wts[t,k] * (y[slot_k] + b2[e_k]) ----------------
__global__ __launch_bounds__(256) void combine_kernel(
    const float* __restrict__ y, const int* __restrict__ slot_of,
    const float* __restrict__ wts, const int* __restrict__ sel,
    const float* __restrict__ b2, float* __restrict__ out)
{
    int t = blockIdx.x, i = threadIdx.x;
    int s0 = slot_of[2*t], s1 = slot_of[2*t+1];
    int e0 = sel[2*t], e1 = sel[2*t+1];
    float w0 = wts[2*t], w1 = wts[2*t+1];
    float4 y0 = ((const float4*)(y + (size_t)s0 * DIM))[i];
    float4 y1 = ((const float4*)(y + (size_t)s1 * DIM))[i];
    float4 c0 = ((const float4*)(b2 + (size_t)e0 * DIM))[i];
    float4 c1 = ((const float4*)(b2 + (size_t)e1 * DIM))[i];
    float4 o;
    o.x = w0 * (y0.x + c0.x) + w1 * (y1.x + c1.x);
    o.y = w0 * (y0.y + c0.y) + w1 * (y1.y + c1.y);
    o.z = w0 * (y0.z + c0.z) + w1 * (y1.z + c1.z);
    o.w = w0 * (y0.w + c0.w) + w1 * (y1.w + c1.w);
    ((float4*)(out + (size_t)t * DIM))[i] = o;
}

extern "C" void kernel_launch(void* const* d_in, const int* in_sizes, int n_in,
                              void* d_out, int out_size, void* d_ws, size_t ws_size,
                              hipStream_t stream)
{
    const float* x    = (const float*)d_in[0];
    const float* gw   = (const float*)d_in[1];
    const float* ln_s = (const float*)d_in[2];
    const float* ln_b = (const float*)d_in[3];
    const float* w1   = (const float*)d_in[4];
    const float* b1   = (const float*)d_in[5];
    const float* w2   = (const float*)d_in[6];
    const float* b2   = (const float*)d_in[7];
    float* out = (float*)d_out;

    char* p = (char*)d_ws;
    auto carve = [&](size_t bytes) -> char* {
        char* r = p;
        p += (bytes + 255) & ~(size_t)255;
        return r;
    };
    int*   counts   = (int*)carve(NE * 4);
    int*   cursor   = (int*)carve(NE * 4);
    int*   off      = (int*)carve((NE + 1) * 4);
    int*   tile_exp = (int*)carve(NTILES * 4);
    int*   sel      = (int*)carve((size_t)T_TOK * 2 * 4);
    float* wts      = (float*)carve((size_t)T_TOK * 2 * 4);
    float* mu_arr   = (float*)carve((size_t)T_TOK * 4);
    float* rstd_arr = (float*)carve((size_t)T_TOK * 4);
    int*   slot_of  = (int*)carve((size_t)T_TOK * 2 * 4);
    _Float16* xg  = (_Float16*)carve((size_t)CAP_ROWS * DIM * 2);  // 35.7 MB
    _Float16* w1t = (_Float16*)carve((size_t)NE * DIM * HID * 2);  // 67.1 MB
    _Float16* w2t = (_Float16*)carve((size_t)NE * DIM * HID * 2);
    _Float16* H1  = (_Float16*)carve((size_t)CAP_ROWS * HID * 2);
    // y aliases xg+w1t (both dead after gemm1); 71.3 MB fits in 102.8 MB region
    float* y = (float*)xg;

    hipMemsetAsync(counts, 0, NE * 4, stream);

    gating_ln_kernel<<<T_TOK, 256, 0, stream>>>(x, gw, sel, wts, mu_arr, rstd_arr, counts);
    build_offsets_kernel<<<1, 1, 0, stream>>>(counts, off, cursor, tile_exp);
    scatter_kernel<<<T_TOK, 256, 0, stream>>>(x, ln_s, ln_b, sel, mu_arr, rstd_arr,
                                              off, cursor, xg, slot_of);
    transpose_cvt_kernel<<<dim3(HID/64, DIM/64, NE), 256, 0, stream>>>(w1, w1t, DIM, HID);
    transpose_cvt_kernel<<<dim3(DIM/64, HID/64, NE), 256, 0, stream>>>(w2, w2t, HID, DIM);

    gemm1_kernel<<<NTILES * 32, 256, 0, stream>>>(xg, w1t, b1, tile_exp, H1);
    gemm2_kernel<<<NTILES * 8, 256, 0, stream>>>(H1, w2t, tile_exp, off, counts, y);
    combine_kernel<<<T_TOK, 256, 0, stream>>>(y, slot_of, wts, sel, b2, out);
}